// Round 10
// baseline (129.519 us; speedup 1.0000x reference)
//
#include <hip/hip_runtime.h>
#include <hip/hip_bf16.h>
#include <math.h>

#define NB 4
#define SEQ 1024
#define DIM 512
#define NH 8
#define HDIM 64
#define HALFW 16
#define KTOP 716
#define THRESH 0.05f
#define PATT 0.3f
#define SCALE 0.125f
#define QKVN 1536

typedef __attribute__((ext_vector_type(8))) short bf16x8;
typedef __attribute__((ext_vector_type(4))) float f32x4;

__device__ __forceinline__ void async_load16(const void* g, void* l) {
  __builtin_amdgcn_global_load_lds(
      (const __attribute__((address_space(1))) void*)g,
      (__attribute__((address_space(3))) void*)l, 16, 0, 0);
}

__device__ __forceinline__ void cvt8(const float* s, __hip_bfloat16* d) {
  float4 a = *(const float4*)s;
  float4 b = *(const float4*)(s + 4);
  union { __hip_bfloat16 h[8]; uint4 u; } o;
  o.h[0] = __float2bfloat16(a.x); o.h[1] = __float2bfloat16(a.y);
  o.h[2] = __float2bfloat16(a.z); o.h[3] = __float2bfloat16(a.w);
  o.h[4] = __float2bfloat16(b.x); o.h[5] = __float2bfloat16(b.y);
  o.h[6] = __float2bfloat16(b.z); o.h[7] = __float2bfloat16(b.w);
  *(uint4*)d = o.u;
}

__device__ __forceinline__ float b2f(short v) {
  return __uint_as_float(((unsigned)(unsigned short)v) << 16);
}

__device__ __forceinline__ float wave_sum(float v) {
#pragma unroll
  for (int m = 32; m >= 1; m >>= 1) v += __shfl_xor(v, m);
  return v;
}

// ---- launch 1: x->bf16 + partial pool (blocks 0..255, 16 rows each),
//                weights->bf16 (blocks 256..511)  -- 2 blocks/CU
__global__ __launch_bounds__(256) void cvt_pool_kernel(
    const float* __restrict__ x, const float* __restrict__ wq,
    const float* __restrict__ wp,
    __hip_bfloat16* __restrict__ xb, __hip_bfloat16* __restrict__ wqb,
    __hip_bfloat16* __restrict__ wpb, float* __restrict__ partial) {
  int bid = blockIdx.x, t = threadIdx.x;
  if (bid < 256) {
    int b = bid >> 6, c = bid & 63;            // 64 chunks x 16 rows per sample
    size_t base = ((size_t)b * SEQ + (size_t)c * 16) * DIM;
    int g = t & 63;          // column group of 8
    int r0 = t >> 6;         // 0..3
    float s[8] = {};
    for (int rr = r0; rr < 16; rr += 4) {
      const float* src = x + base + (size_t)rr * DIM + g * 8;
      float4 a = *(const float4*)src;
      float4 bq = *(const float4*)(src + 4);
      union { __hip_bfloat16 h[8]; uint4 u; } o;
      o.h[0] = __float2bfloat16(a.x); o.h[1] = __float2bfloat16(a.y);
      o.h[2] = __float2bfloat16(a.z); o.h[3] = __float2bfloat16(a.w);
      o.h[4] = __float2bfloat16(bq.x); o.h[5] = __float2bfloat16(bq.y);
      o.h[6] = __float2bfloat16(bq.z); o.h[7] = __float2bfloat16(bq.w);
      *(uint4*)(xb + base + (size_t)rr * DIM + g * 8) = o.u;
      s[0] += a.x; s[1] += a.y; s[2] += a.z; s[3] += a.w;
      s[4] += bq.x; s[5] += bq.y; s[6] += bq.z; s[7] += bq.w;
    }
    __shared__ float red[4][DIM];
#pragma unroll
    for (int u = 0; u < 8; ++u) red[r0][g * 8 + u] = s[u];
    __syncthreads();
    for (int d = t; d < DIM; d += 256)
      partial[(size_t)bid * DIM + d] = red[0][d] + red[1][d] + red[2][d] + red[3][d];
  } else {
    int wi = bid - 256;
#pragma unroll
    for (int u = 0; u < 2; ++u) {
      int gidx = wi * 512 + u * 256 + t;   // 8-elem group index, 131072 total
      if (gidx < 98304) cvt8(wq + (size_t)gidx * 8, wqb + (size_t)gidx * 8);
      else { int j = gidx - 98304; cvt8(wp + (size_t)j * 8, wpb + (size_t)j * 8); }
    }
  }
}

// ---- launch 2: qkv GEMM 128x128 (blocks 0..383) + selector layer-1 (384..895)
__global__ __launch_bounds__(256) void qkv_mlp1_kernel(
    const __hip_bfloat16* __restrict__ A, const __hip_bfloat16* __restrict__ B,
    __hip_bfloat16* __restrict__ C, int N, int K,
    const float* __restrict__ partial, const float* __restrict__ w1,
    const float* __restrict__ b1, float* __restrict__ h1) {
  __shared__ __hip_bfloat16 As[128 * 32];
  __shared__ __hip_bfloat16 Bs[128 * 32];
  __shared__ float pooled[DIM];
  int t = threadIdx.x;
  int bid = blockIdx.x;
  if (bid < 384) {
    int ntiles = N >> 7;                  // 12
    int m0 = (bid / ntiles) * 128;
    int n0 = (bid % ntiles) * 128;
    int w = t >> 6, l = t & 63;
    int wr = w >> 1, wc = w & 1;
    int fm = l & 15, fg = l >> 4;
    f32x4 acc[4][4] = {};
    for (int k0 = 0; k0 < K; k0 += 32) {
#pragma unroll
      for (int i = 0; i < 2; ++i) {
        int s = i * 256 + t;
        int row = s >> 2, cb = (s & 3) << 4;
        async_load16((const char*)(A + (size_t)(m0 + row) * K + k0) + cb,
                     (char*)As + (size_t)s * 16);
        async_load16((const char*)(B + (size_t)(n0 + row) * K + k0) + cb,
                     (char*)Bs + (size_t)s * 16);
      }
      __syncthreads();
      bf16x8 af[4], bf[4];
#pragma unroll
      for (int i = 0; i < 4; ++i)
        af[i] = *(const bf16x8*)(As + (size_t)(wr * 64 + i * 16 + fm) * 32 + fg * 8);
#pragma unroll
      for (int j = 0; j < 4; ++j)
        bf[j] = *(const bf16x8*)(Bs + (size_t)(wc * 64 + j * 16 + fm) * 32 + fg * 8);
#pragma unroll
      for (int i = 0; i < 4; ++i)
#pragma unroll
        for (int j = 0; j < 4; ++j)
          acc[i][j] = __builtin_amdgcn_mfma_f32_16x16x32_bf16(af[i], bf[j], acc[i][j], 0, 0, 0);
      __syncthreads();
    }
    // C/D layout: col=lane&15, row=(lane>>4)*4+reg  [m89-verified]; bf16 store
#pragma unroll
    for (int i = 0; i < 4; ++i) {
      int mbase = m0 + wr * 64 + i * 16 + fg * 4;
#pragma unroll
      for (int j = 0; j < 4; ++j) {
        int n = n0 + wc * 64 + j * 16 + fm;
#pragma unroll
        for (int r = 0; r < 4; ++r)
          C[(size_t)(mbase + r) * N + n] = __float2bfloat16(acc[i][j][r]);
      }
    }
  } else {
    int idx = bid - 384;            // 0..511
    int b = idx >> 7;               // 4 samples x 128 blocks
    int i0 = (idx & 127) << 2;      // 4 outputs per block
    for (int d = t; d < DIM; d += 256) {
      float acc = 0.f;
#pragma unroll 8
      for (int c = 0; c < 64; ++c) acc += partial[(size_t)(b * 64 + c) * DIM + d];
      pooled[d] = acc * (1.0f / SEQ);
    }
    __syncthreads();
    int wv = t >> 6, lane = t & 63;
    int i = i0 + wv;
    const float* w = w1 + (size_t)i * DIM + lane * 8;
    float4 p0 = *(const float4*)(pooled + lane * 8);
    float4 p1 = *(const float4*)(pooled + lane * 8 + 4);
    float4 w0 = *(const float4*)w;
    float4 wx = *(const float4*)(w + 4);
    float acc = fmaf(p0.x, w0.x, fmaf(p0.y, w0.y, fmaf(p0.z, w0.z, p0.w * w0.w)));
    acc = fmaf(p1.x, wx.x, fmaf(p1.y, wx.y, fmaf(p1.z, wx.z, fmaf(p1.w, wx.w, acc))));
    acc = wave_sum(acc);
    if (lane == 0) h1[b * DIM + i] = fmaxf(acc + b1[i], 0.f);
  }
}

// ---- launch 3: selector layer 2 — one wave per output (256 blocks) ----------
__global__ __launch_bounds__(256) void mlp2_kernel(
    const float* __restrict__ h1, const float* __restrict__ w2,
    const float* __restrict__ b2, float* __restrict__ h2) {
  int gw = blockIdx.x * 4 + (threadIdx.x >> 6);   // 1024 waves
  int lane = threadIdx.x & 63;
  int b = gw >> 8, i = gw & 255;
  const float* p = h1 + (size_t)b * DIM + lane * 8;
  const float* w = w2 + (size_t)i * DIM + lane * 8;
  float4 p0 = *(const float4*)p;
  float4 p1 = *(const float4*)(p + 4);
  float4 w0 = *(const float4*)w;
  float4 wv = *(const float4*)(w + 4);
  float acc = fmaf(p0.x, w0.x, fmaf(p0.y, w0.y, fmaf(p0.z, w0.z, p0.w * w0.w)));
  acc = fmaf(p1.x, wv.x, fmaf(p1.y, wv.y, fmaf(p1.z, wv.z, fmaf(p1.w, wv.w, acc))));
  acc = wave_sum(acc);
  if (lane == 0) h2[gw] = fmaxf(acc + b2[i], 0.f);
}

// ---- launch 4: attention — banded MFMA (0..511) + generic 32q (512..1535) ---
__device__ __forceinline__ int block_sum_i(int v, int* red, int t) {
#pragma unroll
  for (int m = 32; m >= 1; m >>= 1) v += __shfl_xor(v, m);
  __syncthreads();
  if ((t & 63) == 0) red[t >> 6] = v;
  __syncthreads();
  return red[0] + red[1] + red[2] + red[3];
}
__device__ __forceinline__ float block_sum_f(float v, float* red, int t) {
#pragma unroll
  for (int m = 32; m >= 1; m >>= 1) v += __shfl_xor(v, m);
  __syncthreads();
  if ((t & 63) == 0) red[t >> 6] = v;
  __syncthreads();
  return red[0] + red[1] + red[2] + red[3];
}
__device__ __forceinline__ float block_max_f(float v, float* red, int t) {
#pragma unroll
  for (int m = 32; m >= 1; m >>= 1) v = fmaxf(v, __shfl_xor(v, m));
  __syncthreads();
  if ((t & 63) == 0) red[t >> 6] = v;
  __syncthreads();
  return fmaxf(fmaxf(red[0], red[1]), fmaxf(red[2], red[3]));
}

// banded LDS (bf16): Ks[96][72] (2-way b128 aliasing = free), Vt[64][120]
// (V^T; cols 96..111 zero guard), Px[4][16][72] with cols 48..63 zeroed.
union AttnSmem {
  struct { short Ks[96][72]; short Vt[64][120]; short Px[4][16][72]; } band;
  struct { float s[SEQ]; float q[HDIM]; unsigned u[SEQ]; int a[SEQ]; int b2[SEQ];
           float rf[4]; int ri[4]; } gen;
};

__global__ __launch_bounds__(256) void attn_kernel(
    const float* __restrict__ h2, const float* __restrict__ w3,
    const float* __restrict__ b3, const float* __restrict__ pbias,
    const __hip_bfloat16* __restrict__ qkvb,
    const float* __restrict__ sw, const float* __restrict__ sb,
    __hip_bfloat16* __restrict__ ao) {
  __shared__ AttnSmem sm;
  __shared__ float fl[8];
  int t = threadIdx.x;
  bool banded = blockIdx.x < 512;
  int bid = banded ? blockIdx.x : blockIdx.x - 512;
  int b = banded ? (bid >> 7) : (bid >> 8);

  // ---- in-block flag computation (wave 0), broadcast via LDS ----
  if (t < 64) {
    float4 hv = *(const float4*)(h2 + (size_t)b * (DIM / 2) + t * 4);
    float lg[3];
#pragma unroll
    for (int o = 0; o < 3; ++o) {
      const float* w = w3 + (size_t)o * (DIM / 2) + t * 4;
      float4 wv = *(const float4*)w;
      float acc = fmaf(hv.x, wv.x, fmaf(hv.y, wv.y, fmaf(hv.z, wv.z, hv.w * wv.w)));
      acc = wave_sum(acc);
      lg[o] = (acc + b3[o] + pbias[o]) * (1.0f / PATT);
    }
    if (t == 0) {
      float m = fmaxf(lg[0], fmaxf(lg[1], lg[2]));
      float e0 = expf(lg[0] - m), e1 = expf(lg[1] - m), e2 = expf(lg[2] - m);
      float s = e0 + e1 + e2;
      float p0 = e0 / s, p1 = e1 / s, p2 = e2 / s;
      fl[0] = p0; fl[1] = p1; fl[2] = p2;
      float cn = (p1 > THRESH) ? 1.f : 0.f;
      float cl = (p0 + p1 > THRESH) ? 1.f : 0.f;
      float cs = (p1 + p2 > THRESH) ? 1.f : 0.f;
      float cls = (p0 + p1 + p2 > THRESH) ? 1.f : 0.f;
      fl[3] = cn; fl[4] = cl; fl[5] = cs; fl[6] = cls;
      fl[7] = ((cls != cl) || (cs != cn)) ? 1.f : 0.f;   // sparse mask matters
    }
  }
  __syncthreads();

  const short* base = (const short*)qkvb + (size_t)b * SEQ * QKVN;

  if (banded) {
    // -------- banded MFMA path: 64 q per block, 4 waves x 16 q --------
    int q64 = bid & 15;
    int h = (bid >> 4) & 7;
    if (fl[7] > 0.5f || fl[3] > 0.5f) return;   // generic handles this sample
    int ho = h * HDIM;
    int q0 = q64 << 6;

    if (fl[4] < 0.5f) {
      // every row fully masked -> one-hot at j=0 -> out = v[...,0,:]
      int d = t & 63;
      short val = base[1024 + ho + d];
      for (int qq = t >> 6; qq < 64; qq += 4)
        *((short*)ao + ((size_t)b * SEQ + q0 + qq) * DIM + ho + d) = val;
      return;
    }

    int w = t >> 6, l = t & 63;
    int fm = l & 15, fg = l >> 4;
    int j0 = q0 - 16;                  // block window start (may be <0)

    // stage K rows [96][64] bf16 (clamped j; OOB masked later in softmax)
    for (int tt = t; tt < 768; tt += 256) {
      int row = tt >> 3, seg = tt & 7;
      int jg = j0 + row;
      jg = jg < 0 ? 0 : (jg > SEQ - 1 ? SEQ - 1 : jg);
      bf16x8 kv = *(const bf16x8*)(base + (size_t)jg * QKVN + 512 + ho + seg * 8);
      *(bf16x8*)&sm.band.Ks[row][seg * 8] = kv;
    }
    // stage V transposed: Vt[d][row] = V[j0+row][d]
    for (int tt = t; tt < 768; tt += 256) {
      int row = tt % 96, seg = tt / 96;
      int jg = j0 + row;
      jg = jg < 0 ? 0 : (jg > SEQ - 1 ? SEQ - 1 : jg);
      union { bf16x8 v; short s[8]; } vv;
      vv.v = *(const bf16x8*)(base + (size_t)jg * QKVN + 1024 + ho + seg * 8);
      int d0 = seg * 8;
#pragma unroll
      for (int i = 0; i < 8; ++i) sm.band.Vt[d0 + i][row] = vv.s[i];
    }
    // zero Vt guard cols 96..111
    {
      int r = t >> 2, cg = (t & 3) << 2;
      *(uint2*)&sm.band.Vt[r][96 + cg] = make_uint2(0u, 0u);
    }
    // zero Px pad cols 48..63
    {
      int r = l >> 2, cg = (l & 3) << 2;
      *(uint2*)&sm.band.Px[w][r][48 + cg] = make_uint2(0u, 0u);
    }
    // Q A-frags straight from global bf16
    bf16x8 aq[2];
    {
      int qrow = q0 + w * 16 + fm;
      const short* qsrc = base + (size_t)qrow * QKVN + ho;
#pragma unroll
      for (int c = 0; c < 2; ++c) aq[c] = *(const bf16x8*)(qsrc + c * 32 + fg * 8);
    }
    __syncthreads();

    // S = Q @ K^T : 3 j-tiles x 2 k-chunks of 16x16x32 MFMA
    f32x4 sacc[3] = {};
#pragma unroll
    for (int jt = 0; jt < 3; ++jt)
#pragma unroll
      for (int c = 0; c < 2; ++c) {
        bf16x8 bk = *(const bf16x8*)&sm.band.Ks[w * 16 + jt * 16 + fm][c * 32 + fg * 8];
        sacc[jt] = __builtin_amdgcn_mfma_f32_16x16x32_bf16(aq[c], bk, sacc[jt], 0, 0, 0);
      }
    // in-register softmax. C-layout: row q = fg*4+r, col j = jt*16+fm.
#pragma unroll
    for (int r = 0; r < 4; ++r) {
      int ql = fg * 4 + r;
      float sv[3], mx = -INFINITY;
#pragma unroll
      for (int jt = 0; jt < 3; ++jt) {
        int jl = jt * 16 + fm;
        int jg = j0 + w * 16 + jl;
        int d = jl - ql;   // j - q + 16
        bool valid = (d >= 0) && (d <= 32) && (jg >= 0) && (jg < SEQ);
        sv[jt] = valid ? sacc[jt][r] * SCALE : -INFINITY;
        mx = fmaxf(mx, sv[jt]);
      }
#pragma unroll
      for (int msk = 8; msk >= 1; msk >>= 1) mx = fmaxf(mx, __shfl_xor(mx, msk));
      float pv[3], sum = 0.f;
#pragma unroll
      for (int jt = 0; jt < 3; ++jt) {
        float p = (sv[jt] == -INFINITY) ? 0.f : expf(sv[jt] - mx);
        pv[jt] = p; sum += p;
      }
#pragma unroll
      for (int msk = 8; msk >= 1; msk >>= 1) sum += __shfl_xor(sum, msk);
      float inv = 1.f / sum;
#pragma unroll
      for (int jt = 0; jt < 3; ++jt) {
        union { __hip_bfloat16 hh; short ss; } cv;
        cv.hh = __float2bfloat16(pv[jt] * inv);
        sm.band.Px[w][ql][jt * 16 + fm] = cv.ss;
      }
    }
    // O = P @ V : A-frags from Px, B-frags from Vt (both bf16, direct b128)
    bf16x8 pa[2];
#pragma unroll
    for (int c = 0; c < 2; ++c)
      pa[c] = *(const bf16x8*)&sm.band.Px[w][fm][c * 32 + fg * 8];
    f32x4 oacc[4] = {};
#pragma unroll
    for (int dt = 0; dt < 4; ++dt)
#pragma unroll
      for (int c = 0; c < 2; ++c) {
        bf16x8 bv = *(const bf16x8*)&sm.band.Vt[dt * 16 + fm][w * 16 + c * 32 + fg * 8];
        oacc[dt] = __builtin_amdgcn_mfma_f32_16x16x32_bf16(pa[c], bv, oacc[dt], 0, 0, 0);
      }
    // write out: row q = fg*4+r, col d = dt*16+fm
#pragma unroll
    for (int dt = 0; dt < 4; ++dt)
#pragma unroll
      for (int r = 0; r < 4; ++r) {
        int qg = q0 + w * 16 + fg * 4 + r;
        ao[((size_t)b * SEQ + qg) * DIM + ho + dt * 16 + fm] =
            __float2bfloat16(oacc[dt][r]);
      }
  } else {
    // -------- generic fallback: 32 q per block (1024 blocks) --------
    int qg = bid & 31;
    int h = (bid >> 5) & 7;
    bool need_sparse = fl[7] > 0.5f;
    bool cn_b = fl[3] > 0.5f;
    if (!(need_sparse || cn_b)) return;

    int ho = h * HDIM;
    float c_n = fl[3], c_l = fl[4], c_s = fl[5], c_ls = fl[6];
    float swh = sw[h], sbh = sb[h];

    float* s_sh = sm.gen.s;
    float* q_sh = sm.gen.q;
    unsigned* u_sh = sm.gen.u;
    int* sc_a = sm.gen.a;
    int* sc_b = sm.gen.b2;
    float* redf = sm.gen.rf;
    int* redi = sm.gen.ri;

    for (int qi = 0; qi < 32; ++qi) {
      int q = qg * 32 + qi;
      if (t < HDIM) q_sh[t] = b2f(base[(size_t)q * QKVN + ho + t]);
      __syncthreads();
      for (int j = t; j < SEQ; j += 256) {
        const short* kr = base + (size_t)j * QKVN + 512 + ho;
        float acc = 0.f;
#pragma unroll
        for (int c = 0; c < 8; ++c) {
          union { bf16x8 v; short s[8]; } kv;
          kv.v = *(const bf16x8*)(kr + c * 8);
#pragma unroll
          for (int i = 0; i < 8; ++i)
            acc = fmaf(q_sh[c * 8 + i], b2f(kv.s[i]), acc);
        }
        s_sh[j] = acc * SCALE;
      }
      __syncthreads();

      if (need_sparse) {
        for (int j = t; j < SEQ; j += 256) {
          unsigned bits = __float_as_uint(fmaf(s_sh[j], swh, sbh));
          u_sh[j] = bits ^ ((bits & 0x80000000u) ? 0xFFFFFFFFu : 0x80000000u);
        }
        __syncthreads();
        unsigned V = 0u;
        for (int bit = 31; bit >= 0; --bit) {
          unsigned cand = V | (1u << bit);
          int c = 0;
          for (int j = t; j < SEQ; j += 256) c += (u_sh[j] >= cand) ? 1 : 0;
          c = block_sum_i(c, redi, t);
          if (c >= KTOP) V = cand;
        }
        int g = 0;
        for (int j = t; j < SEQ; j += 256) g += (u_sh[j] > V) ? 1 : 0;
        g = block_sum_i(g, redi, t);
        int r = KTOP - g;
        for (int j = t; j < SEQ; j += 256) sc_a[j] = (u_sh[j] == V) ? 1 : 0;
        __syncthreads();
        int* src = sc_a; int* dst = sc_b;
        for (int off = 1; off < SEQ; off <<= 1) {
          for (int j = t; j < SEQ; j += 256)
            dst[j] = src[j] + ((j >= off) ? src[j - off] : 0);
          __syncthreads();
          int* tmp = src; src = dst; dst = tmp;
        }
        for (int j = t; j < SEQ; j += 256) {
          bool sp = (u_sh[j] > V) || ((u_sh[j] == V) && (src[j] - 1 < r));
          bool local = (j >= q - HALFW) && (j <= q + HALFW);
          float cv = local ? (sp ? c_ls : c_l) : (sp ? c_s : c_n);
          if (cv < 0.5f) s_sh[j] = -INFINITY;
        }
      } else {
        for (int j = t; j < SEQ; j += 256) {
          bool local = (j >= q - HALFW) && (j <= q + HALFW);
          float cv = local ? c_l : c_n;
          if (cv < 0.5f) s_sh[j] = -INFINITY;
        }
      }
      __syncthreads();

      int anyc = 0;
      for (int j = t; j < SEQ; j += 256) anyc += (s_sh[j] != -INFINITY) ? 1 : 0;
      anyc = block_sum_i(anyc, redi, t);
      if (anyc == 0 && t == 0) s_sh[0] = 0.f;
      __syncthreads();

      float mx = -INFINITY;
      for (int j = t; j < SEQ; j += 256) mx = fmaxf(mx, s_sh[j]);
      mx = block_max_f(mx, redf, t);
      float ls = 0.f;
      for (int j = t; j < SEQ; j += 256) {
        float p = (s_sh[j] == -INFINITY) ? 0.f : expf(s_sh[j] - mx);
        s_sh[j] = p; ls += p;
      }
      ls = block_sum_f(ls, redf, t);
      float inv = 1.f / ls;

      int dd = t & 63, jg2 = t >> 6;
      float acc = 0.f;
      for (int j = jg2; j < SEQ; j += 4)
        acc = fmaf(s_sh[j] * inv, b2f(base[(size_t)j * QKVN + 1024 + ho + dd]), acc);
      float* redo = (float*)u_sh;
      __syncthreads();
      redo[t] = acc;
      __syncthreads();
      if (t < 64) {
        float o = redo[t] + redo[t + 64] + redo[t + 128] + redo[t + 192];
        ao[((size_t)b * SEQ + q) * DIM + ho + t] = __float2bfloat16(o);
      }
      __syncthreads();
    }
  }
}

// ---- launch 5: proj GEMM, 64x64 tile (512 blocks = 2/CU) --------------------
__global__ __launch_bounds__(256) void proj_gemm_kernel(
    const __hip_bfloat16* __restrict__ A, const __hip_bfloat16* __restrict__ B,
    const float* __restrict__ bias, float* __restrict__ C,
    int N, int K) {
  __shared__ __hip_bfloat16 As[64 * 32];
  __shared__ __hip_bfloat16 Bs[64 * 32];
  int t = threadIdx.x;
  int m0 = blockIdx.y * 64;
  int n0 = blockIdx.x * 64;
  int w = t >> 6, l = t & 63;
  int fm = l & 15, fg = l >> 4;
  f32x4 acc[4] = {};
  for (int k0 = 0; k0 < K; k0 += 32) {
    int row = t >> 2, cb = (t & 3) << 4;
    async_load16((const char*)(A + (size_t)(m0 + row) * K + k0) + cb,
                 (char*)As + (size_t)t * 16);
    async_load16((const char*)(B + (size_t)(n0 + row) * K + k0) + cb,
                 (char*)Bs + (size_t)t * 16);
    __syncthreads();
    bf16x8 af = *(const bf16x8*)(As + (size_t)(w * 16 + fm) * 32 + fg * 8);
    bf16x8 bf[4];
#pragma unroll
    for (int j = 0; j < 4; ++j)
      bf[j] = *(const bf16x8*)(Bs + (size_t)(j * 16 + fm) * 32 + fg * 8);
#pragma unroll
    for (int j = 0; j < 4; ++j)
      acc[j] = __builtin_amdgcn_mfma_f32_16x16x32_bf16(af, bf[j], acc[j], 0, 0, 0);
    __syncthreads();
  }
  // C/D layout: col=lane&15, row=(lane>>4)*4+reg
  int mbase = m0 + w * 16 + fg * 4;
#pragma unroll
  for (int j = 0; j < 4; ++j) {
    int n = n0 + j * 16 + fm;
    float bv = bias[n];
#pragma unroll
    for (int r = 0; r < 4; ++r)
      C[(size_t)(mbase + r) * N + n] = acc[j][r] + bv;
  }
}

extern "C" void kernel_launch(void* const* d_in, const int* in_sizes, int n_in,
                              void* d_out, int out_size, void* d_ws, size_t ws_size,
                              hipStream_t stream) {
  const float* x      = (const float*)d_in[0];
  const float* qkv_w  = (const float*)d_in[1];
  const float* proj_w = (const float*)d_in[2];
  const float* proj_b = (const float*)d_in[3];
  const float* ps_w1  = (const float*)d_in[4];
  const float* ps_b1  = (const float*)d_in[5];
  const float* ps_w2  = (const float*)d_in[6];
  const float* ps_b2  = (const float*)d_in[7];
  const float* ps_w3  = (const float*)d_in[8];
  const float* ps_b3  = (const float*)d_in[9];
  const float* pbias  = (const float*)d_in[10];
  const float* sw     = (const float*)d_in[11];
  const float* sb     = (const float*)d_in[12];
  float* out = (float*)d_out;

  char* w = (char*)d_ws;
  float* partial = (float*)w;            w += (size_t)NB * 64 * DIM * 4;
  float* h1 = (float*)w;                 w += (size_t)NB * DIM * 4;
  float* h2 = (float*)w;                 w += (size_t)NB * (DIM / 2) * 4;
  __hip_bfloat16* qkvb = (__hip_bfloat16*)w; w += (size_t)NB * SEQ * QKVN * 2;
  __hip_bfloat16* xb  = (__hip_bfloat16*)w;  w += (size_t)NB * SEQ * DIM * 2;
  __hip_bfloat16* wqb = (__hip_bfloat16*)w;  w += (size_t)QKVN * DIM * 2;
  __hip_bfloat16* wpb = (__hip_bfloat16*)w;  w += (size_t)DIM * DIM * 2;
  __hip_bfloat16* aob = (__hip_bfloat16*)w;  w += (size_t)NB * SEQ * DIM * 2;

  hipLaunchKernelGGL(cvt_pool_kernel, dim3(512), dim3(256), 0, stream,
                     x, qkv_w, proj_w, xb, wqb, wpb, partial);
  hipLaunchKernelGGL(qkv_mlp1_kernel, dim3(384 + 512), dim3(256), 0, stream,
                     xb, wqb, qkvb, QKVN, DIM, partial, ps_w1, ps_b1, h1);
  hipLaunchKernelGGL(mlp2_kernel, dim3(256), dim3(256), 0, stream,
                     h1, ps_w2, ps_b2, h2);
  hipLaunchKernelGGL(attn_kernel, dim3(512 + 1024), dim3(256), 0, stream,
                     h2, ps_w3, ps_b3, pbias, qkvb, sw, sb, aob);
  hipLaunchKernelGGL(proj_gemm_kernel, dim3(DIM / 64, (NB * SEQ) / 64), dim3(256), 0, stream,
                     aob, wpb, proj_b, out, DIM, DIM);
}

// Round 11
// 126.999 us; speedup vs baseline: 1.0198x; 1.0198x over previous
//
#include <hip/hip_runtime.h>
#include <hip/hip_bf16.h>
#include <math.h>

#define NB 4
#define SEQ 1024
#define DIM 512
#define NH 8
#define HDIM 64
#define HALFW 16
#define KTOP 716
#define THRESH 0.05f
#define PATT 0.3f
#define SCALE 0.125f
#define QKVN 1536

typedef __attribute__((ext_vector_type(8))) short bf16x8;
typedef __attribute__((ext_vector_type(4))) float f32x4;

__device__ __forceinline__ void async_load16(const void* g, void* l) {
  __builtin_amdgcn_global_load_lds(
      (const __attribute__((address_space(1))) void*)g,
      (__attribute__((address_space(3))) void*)l, 16, 0, 0);
}

__device__ __forceinline__ void cvt8(const float* s, __hip_bfloat16* d) {
  float4 a = *(const float4*)s;
  float4 b = *(const float4*)(s + 4);
  union { __hip_bfloat16 h[8]; uint4 u; } o;
  o.h[0] = __float2bfloat16(a.x); o.h[1] = __float2bfloat16(a.y);
  o.h[2] = __float2bfloat16(a.z); o.h[3] = __float2bfloat16(a.w);
  o.h[4] = __float2bfloat16(b.x); o.h[5] = __float2bfloat16(b.y);
  o.h[6] = __float2bfloat16(b.z); o.h[7] = __float2bfloat16(b.w);
  *(uint4*)d = o.u;
}

__device__ __forceinline__ float b2f(short v) {
  return __uint_as_float(((unsigned)(unsigned short)v) << 16);
}

__device__ __forceinline__ float wave_sum(float v) {
#pragma unroll
  for (int m = 32; m >= 1; m >>= 1) v += __shfl_xor(v, m);
  return v;
}

// ---- launch 1: x->bf16 + partial pool (blocks 0..255, 16 rows each),
//                weights->bf16 (blocks 256..511)  -- 2 blocks/CU
__global__ __launch_bounds__(256) void cvt_pool_kernel(
    const float* __restrict__ x, const float* __restrict__ wq,
    const float* __restrict__ wp,
    __hip_bfloat16* __restrict__ xb, __hip_bfloat16* __restrict__ wqb,
    __hip_bfloat16* __restrict__ wpb, float* __restrict__ partial) {
  int bid = blockIdx.x, t = threadIdx.x;
  if (bid < 256) {
    int b = bid >> 6, c = bid & 63;            // 64 chunks x 16 rows per sample
    size_t base = ((size_t)b * SEQ + (size_t)c * 16) * DIM;
    int g = t & 63;          // column group of 8
    int r0 = t >> 6;         // 0..3
    float s[8] = {};
    for (int rr = r0; rr < 16; rr += 4) {
      const float* src = x + base + (size_t)rr * DIM + g * 8;
      float4 a = *(const float4*)src;
      float4 bq = *(const float4*)(src + 4);
      union { __hip_bfloat16 h[8]; uint4 u; } o;
      o.h[0] = __float2bfloat16(a.x); o.h[1] = __float2bfloat16(a.y);
      o.h[2] = __float2bfloat16(a.z); o.h[3] = __float2bfloat16(a.w);
      o.h[4] = __float2bfloat16(bq.x); o.h[5] = __float2bfloat16(bq.y);
      o.h[6] = __float2bfloat16(bq.z); o.h[7] = __float2bfloat16(bq.w);
      *(uint4*)(xb + base + (size_t)rr * DIM + g * 8) = o.u;
      s[0] += a.x; s[1] += a.y; s[2] += a.z; s[3] += a.w;
      s[4] += bq.x; s[5] += bq.y; s[6] += bq.z; s[7] += bq.w;
    }
    __shared__ float red[4][DIM];
#pragma unroll
    for (int u = 0; u < 8; ++u) red[r0][g * 8 + u] = s[u];
    __syncthreads();
    for (int d = t; d < DIM; d += 256)
      partial[(size_t)bid * DIM + d] = red[0][d] + red[1][d] + red[2][d] + red[3][d];
  } else {
    int wi = bid - 256;
#pragma unroll
    for (int u = 0; u < 2; ++u) {
      int gidx = wi * 512 + u * 256 + t;   // 8-elem group index, 131072 total
      if (gidx < 98304) cvt8(wq + (size_t)gidx * 8, wqb + (size_t)gidx * 8);
      else { int j = gidx - 98304; cvt8(wp + (size_t)j * 8, wpb + (size_t)j * 8); }
    }
  }
}

// ---- launch 2: qkv GEMM 128x64 (blocks 0..767) + selector layer-1 (768..1279)
__global__ __launch_bounds__(256) void qkv_mlp1_kernel(
    const __hip_bfloat16* __restrict__ A, const __hip_bfloat16* __restrict__ B,
    __hip_bfloat16* __restrict__ C, int N, int K,
    const float* __restrict__ partial, const float* __restrict__ w1,
    const float* __restrict__ b1, float* __restrict__ h1) {
  __shared__ __hip_bfloat16 As[128 * 32];
  __shared__ __hip_bfloat16 Bs[64 * 32];
  __shared__ float pooled[DIM];
  int t = threadIdx.x;
  int bid = blockIdx.x;
  if (bid < 768) {
    int ntiles = N >> 6;                  // 24
    int m0 = (bid / ntiles) * 128;
    int n0 = (bid % ntiles) * 64;
    int w = t >> 6, l = t & 63;
    int fm = l & 15, fg = l >> 4;
    f32x4 acc[2][4] = {};
    for (int k0 = 0; k0 < K; k0 += 32) {
#pragma unroll
      for (int i = 0; i < 2; ++i) {
        int s = i * 256 + t;
        int row = s >> 2, cb = (s & 3) << 4;
        async_load16((const char*)(A + (size_t)(m0 + row) * K + k0) + cb,
                     (char*)As + (size_t)s * 16);
      }
      {
        int row = t >> 2, cb = (t & 3) << 4;
        async_load16((const char*)(B + (size_t)(n0 + row) * K + k0) + cb,
                     (char*)Bs + (size_t)t * 16);
      }
      __syncthreads();
      bf16x8 af[2], bf[4];
#pragma unroll
      for (int i = 0; i < 2; ++i)
        af[i] = *(const bf16x8*)(As + (size_t)(w * 32 + i * 16 + fm) * 32 + fg * 8);
#pragma unroll
      for (int j = 0; j < 4; ++j)
        bf[j] = *(const bf16x8*)(Bs + (size_t)(j * 16 + fm) * 32 + fg * 8);
#pragma unroll
      for (int i = 0; i < 2; ++i)
#pragma unroll
        for (int j = 0; j < 4; ++j)
          acc[i][j] = __builtin_amdgcn_mfma_f32_16x16x32_bf16(af[i], bf[j], acc[i][j], 0, 0, 0);
      __syncthreads();
    }
    // C/D layout: col=lane&15, row=(lane>>4)*4+reg  [m89-verified]; bf16 store
#pragma unroll
    for (int i = 0; i < 2; ++i) {
      int mbase = m0 + w * 32 + i * 16 + fg * 4;
#pragma unroll
      for (int j = 0; j < 4; ++j) {
        int n = n0 + j * 16 + fm;
#pragma unroll
        for (int r = 0; r < 4; ++r)
          C[(size_t)(mbase + r) * N + n] = __float2bfloat16(acc[i][j][r]);
      }
    }
  } else {
    int idx = bid - 768;            // 0..511
    int b = idx >> 7;               // 4 samples x 128 blocks
    int i0 = (idx & 127) << 2;      // 4 outputs per block
    for (int d = t; d < DIM; d += 256) {
      float acc = 0.f;
#pragma unroll 8
      for (int c = 0; c < 64; ++c) acc += partial[(size_t)(b * 64 + c) * DIM + d];
      pooled[d] = acc * (1.0f / SEQ);
    }
    __syncthreads();
    int wv = t >> 6, lane = t & 63;
    int i = i0 + wv;
    const float* w = w1 + (size_t)i * DIM + lane * 8;
    float4 p0 = *(const float4*)(pooled + lane * 8);
    float4 p1 = *(const float4*)(pooled + lane * 8 + 4);
    float4 w0 = *(const float4*)w;
    float4 wx = *(const float4*)(w + 4);
    float acc = fmaf(p0.x, w0.x, fmaf(p0.y, w0.y, fmaf(p0.z, w0.z, p0.w * w0.w)));
    acc = fmaf(p1.x, wx.x, fmaf(p1.y, wx.y, fmaf(p1.z, wx.z, fmaf(p1.w, wx.w, acc))));
    acc = wave_sum(acc);
    if (lane == 0) h1[b * DIM + i] = fmaxf(acc + b1[i], 0.f);
  }
}

// ---- launch 3: selector layer 2 — one wave per output (256 blocks) ----------
__global__ __launch_bounds__(256) void mlp2_kernel(
    const float* __restrict__ h1, const float* __restrict__ w2,
    const float* __restrict__ b2, float* __restrict__ h2) {
  int gw = blockIdx.x * 4 + (threadIdx.x >> 6);   // 1024 waves
  int lane = threadIdx.x & 63;
  int b = gw >> 8, i = gw & 255;
  const float* p = h1 + (size_t)b * DIM + lane * 8;
  const float* w = w2 + (size_t)i * DIM + lane * 8;
  float4 p0 = *(const float4*)p;
  float4 p1 = *(const float4*)(p + 4);
  float4 w0 = *(const float4*)w;
  float4 wv = *(const float4*)(w + 4);
  float acc = fmaf(p0.x, w0.x, fmaf(p0.y, w0.y, fmaf(p0.z, w0.z, p0.w * w0.w)));
  acc = fmaf(p1.x, wv.x, fmaf(p1.y, wv.y, fmaf(p1.z, wv.z, fmaf(p1.w, wv.w, acc))));
  acc = wave_sum(acc);
  if (lane == 0) h2[gw] = fmaxf(acc + b2[i], 0.f);
}

// ---- launch 4: attention — banded MFMA (0..511) + generic 32q (512..1535) ---
__device__ __forceinline__ int block_sum_i(int v, int* red, int t) {
#pragma unroll
  for (int m = 32; m >= 1; m >>= 1) v += __shfl_xor(v, m);
  __syncthreads();
  if ((t & 63) == 0) red[t >> 6] = v;
  __syncthreads();
  return red[0] + red[1] + red[2] + red[3];
}
__device__ __forceinline__ float block_sum_f(float v, float* red, int t) {
#pragma unroll
  for (int m = 32; m >= 1; m >>= 1) v += __shfl_xor(v, m);
  __syncthreads();
  if ((t & 63) == 0) red[t >> 6] = v;
  __syncthreads();
  return red[0] + red[1] + red[2] + red[3];
}
__device__ __forceinline__ float block_max_f(float v, float* red, int t) {
#pragma unroll
  for (int m = 32; m >= 1; m >>= 1) v = fmaxf(v, __shfl_xor(v, m));
  __syncthreads();
  if ((t & 63) == 0) red[t >> 6] = v;
  __syncthreads();
  return fmaxf(fmaxf(red[0], red[1]), fmaxf(red[2], red[3]));
}

// banded LDS (bf16): Ks[96][72] (2-way b128 aliasing = free), Vt[64][120]
// (V^T; cols 96..111 zero guard), Px[4][16][72] with cols 48..63 zeroed.
union AttnSmem {
  struct { short Ks[96][72]; short Vt[64][120]; short Px[4][16][72]; } band;
  struct { float s[SEQ]; float q[HDIM]; unsigned u[SEQ]; int a[SEQ]; int b2[SEQ];
           float rf[4]; int ri[4]; } gen;
};

__global__ __launch_bounds__(256) void attn_kernel(
    const float* __restrict__ h2, const float* __restrict__ w3,
    const float* __restrict__ b3, const float* __restrict__ pbias,
    const __hip_bfloat16* __restrict__ qkvb,
    const float* __restrict__ sw, const float* __restrict__ sb,
    __hip_bfloat16* __restrict__ ao) {
  __shared__ AttnSmem sm;
  __shared__ float fl[8];
  int t = threadIdx.x;
  bool banded = blockIdx.x < 512;
  int bid = banded ? blockIdx.x : blockIdx.x - 512;
  int b = banded ? (bid >> 7) : (bid >> 8);

  // ---- in-block flag computation (wave 0), broadcast via LDS ----
  if (t < 64) {
    float4 hv = *(const float4*)(h2 + (size_t)b * (DIM / 2) + t * 4);
    float lg[3];
#pragma unroll
    for (int o = 0; o < 3; ++o) {
      const float* w = w3 + (size_t)o * (DIM / 2) + t * 4;
      float4 wv = *(const float4*)w;
      float acc = fmaf(hv.x, wv.x, fmaf(hv.y, wv.y, fmaf(hv.z, wv.z, hv.w * wv.w)));
      acc = wave_sum(acc);
      lg[o] = (acc + b3[o] + pbias[o]) * (1.0f / PATT);
    }
    if (t == 0) {
      float m = fmaxf(lg[0], fmaxf(lg[1], lg[2]));
      float e0 = expf(lg[0] - m), e1 = expf(lg[1] - m), e2 = expf(lg[2] - m);
      float s = e0 + e1 + e2;
      float p0 = e0 / s, p1 = e1 / s, p2 = e2 / s;
      fl[0] = p0; fl[1] = p1; fl[2] = p2;
      float cn = (p1 > THRESH) ? 1.f : 0.f;
      float cl = (p0 + p1 > THRESH) ? 1.f : 0.f;
      float cs = (p1 + p2 > THRESH) ? 1.f : 0.f;
      float cls = (p0 + p1 + p2 > THRESH) ? 1.f : 0.f;
      fl[3] = cn; fl[4] = cl; fl[5] = cs; fl[6] = cls;
      fl[7] = ((cls != cl) || (cs != cn)) ? 1.f : 0.f;   // sparse mask matters
    }
  }
  __syncthreads();

  const short* base = (const short*)qkvb + (size_t)b * SEQ * QKVN;

  if (banded) {
    // -------- banded MFMA path: 64 q per block, 4 waves x 16 q --------
    int q64 = bid & 15;
    int h = (bid >> 4) & 7;
    if (fl[7] > 0.5f || fl[3] > 0.5f) return;   // generic handles this sample
    int ho = h * HDIM;
    int q0 = q64 << 6;

    if (fl[4] < 0.5f) {
      // every row fully masked -> one-hot at j=0 -> out = v[...,0,:]
      int d = t & 63;
      short val = base[1024 + ho + d];
      for (int qq = t >> 6; qq < 64; qq += 4)
        *((short*)ao + ((size_t)b * SEQ + q0 + qq) * DIM + ho + d) = val;
      return;
    }

    int w = t >> 6, l = t & 63;
    int fm = l & 15, fg = l >> 4;
    int j0 = q0 - 16;                  // block window start (may be <0)

    // stage K rows [96][64] bf16 (clamped j; OOB masked later in softmax)
    for (int tt = t; tt < 768; tt += 256) {
      int row = tt >> 3, seg = tt & 7;
      int jg = j0 + row;
      jg = jg < 0 ? 0 : (jg > SEQ - 1 ? SEQ - 1 : jg);
      bf16x8 kv = *(const bf16x8*)(base + (size_t)jg * QKVN + 512 + ho + seg * 8);
      *(bf16x8*)&sm.band.Ks[row][seg * 8] = kv;
    }
    // stage V transposed: Vt[d][row] = V[j0+row][d]
    for (int tt = t; tt < 768; tt += 256) {
      int row = tt % 96, seg = tt / 96;
      int jg = j0 + row;
      jg = jg < 0 ? 0 : (jg > SEQ - 1 ? SEQ - 1 : jg);
      union { bf16x8 v; short s[8]; } vv;
      vv.v = *(const bf16x8*)(base + (size_t)jg * QKVN + 1024 + ho + seg * 8);
      int d0 = seg * 8;
#pragma unroll
      for (int i = 0; i < 8; ++i) sm.band.Vt[d0 + i][row] = vv.s[i];
    }
    // zero Vt guard cols 96..111
    {
      int r = t >> 2, cg = (t & 3) << 2;
      *(uint2*)&sm.band.Vt[r][96 + cg] = make_uint2(0u, 0u);
    }
    // zero Px pad cols 48..63
    {
      int r = l >> 2, cg = (l & 3) << 2;
      *(uint2*)&sm.band.Px[w][r][48 + cg] = make_uint2(0u, 0u);
    }
    // Q A-frags straight from global bf16
    bf16x8 aq[2];
    {
      int qrow = q0 + w * 16 + fm;
      const short* qsrc = base + (size_t)qrow * QKVN + ho;
#pragma unroll
      for (int c = 0; c < 2; ++c) aq[c] = *(const bf16x8*)(qsrc + c * 32 + fg * 8);
    }
    __syncthreads();

    // S = Q @ K^T : 3 j-tiles x 2 k-chunks of 16x16x32 MFMA
    f32x4 sacc[3] = {};
#pragma unroll
    for (int jt = 0; jt < 3; ++jt)
#pragma unroll
      for (int c = 0; c < 2; ++c) {
        bf16x8 bk = *(const bf16x8*)&sm.band.Ks[w * 16 + jt * 16 + fm][c * 32 + fg * 8];
        sacc[jt] = __builtin_amdgcn_mfma_f32_16x16x32_bf16(aq[c], bk, sacc[jt], 0, 0, 0);
      }
    // in-register softmax. C-layout: row q = fg*4+r, col j = jt*16+fm.
#pragma unroll
    for (int r = 0; r < 4; ++r) {
      int ql = fg * 4 + r;
      float sv[3], mx = -INFINITY;
#pragma unroll
      for (int jt = 0; jt < 3; ++jt) {
        int jl = jt * 16 + fm;
        int jg = j0 + w * 16 + jl;
        int d = jl - ql;   // j - q + 16
        bool valid = (d >= 0) && (d <= 32) && (jg >= 0) && (jg < SEQ);
        sv[jt] = valid ? sacc[jt][r] * SCALE : -INFINITY;
        mx = fmaxf(mx, sv[jt]);
      }
#pragma unroll
      for (int msk = 8; msk >= 1; msk >>= 1) mx = fmaxf(mx, __shfl_xor(mx, msk));
      float pv[3], sum = 0.f;
#pragma unroll
      for (int jt = 0; jt < 3; ++jt) {
        float p = (sv[jt] == -INFINITY) ? 0.f : expf(sv[jt] - mx);
        pv[jt] = p; sum += p;
      }
#pragma unroll
      for (int msk = 8; msk >= 1; msk >>= 1) sum += __shfl_xor(sum, msk);
      float inv = 1.f / sum;
#pragma unroll
      for (int jt = 0; jt < 3; ++jt) {
        union { __hip_bfloat16 hh; short ss; } cv;
        cv.hh = __float2bfloat16(pv[jt] * inv);
        sm.band.Px[w][ql][jt * 16 + fm] = cv.ss;
      }
    }
    // O = P @ V : A-frags from Px, B-frags from Vt (both bf16, direct b128)
    bf16x8 pa[2];
#pragma unroll
    for (int c = 0; c < 2; ++c)
      pa[c] = *(const bf16x8*)&sm.band.Px[w][fm][c * 32 + fg * 8];
    f32x4 oacc[4] = {};
#pragma unroll
    for (int dt = 0; dt < 4; ++dt)
#pragma unroll
      for (int c = 0; c < 2; ++c) {
        bf16x8 bv = *(const bf16x8*)&sm.band.Vt[dt * 16 + fm][w * 16 + c * 32 + fg * 8];
        oacc[dt] = __builtin_amdgcn_mfma_f32_16x16x32_bf16(pa[c], bv, oacc[dt], 0, 0, 0);
      }
    // write out: row q = fg*4+r, col d = dt*16+fm
#pragma unroll
    for (int dt = 0; dt < 4; ++dt)
#pragma unroll
      for (int r = 0; r < 4; ++r) {
        int qg = q0 + w * 16 + fg * 4 + r;
        ao[((size_t)b * SEQ + qg) * DIM + ho + dt * 16 + fm] =
            __float2bfloat16(oacc[dt][r]);
      }
  } else {
    // -------- generic fallback: 32 q per block (1024 blocks) --------
    int qg = bid & 31;
    int h = (bid >> 5) & 7;
    bool need_sparse = fl[7] > 0.5f;
    bool cn_b = fl[3] > 0.5f;
    if (!(need_sparse || cn_b)) return;

    int ho = h * HDIM;
    float c_n = fl[3], c_l = fl[4], c_s = fl[5], c_ls = fl[6];
    float swh = sw[h], sbh = sb[h];

    float* s_sh = sm.gen.s;
    float* q_sh = sm.gen.q;
    unsigned* u_sh = sm.gen.u;
    int* sc_a = sm.gen.a;
    int* sc_b = sm.gen.b2;
    float* redf = sm.gen.rf;
    int* redi = sm.gen.ri;

    for (int qi = 0; qi < 32; ++qi) {
      int q = qg * 32 + qi;
      if (t < HDIM) q_sh[t] = b2f(base[(size_t)q * QKVN + ho + t]);
      __syncthreads();
      for (int j = t; j < SEQ; j += 256) {
        const short* kr = base + (size_t)j * QKVN + 512 + ho;
        float acc = 0.f;
#pragma unroll
        for (int c = 0; c < 8; ++c) {
          union { bf16x8 v; short s[8]; } kv;
          kv.v = *(const bf16x8*)(kr + c * 8);
#pragma unroll
          for (int i = 0; i < 8; ++i)
            acc = fmaf(q_sh[c * 8 + i], b2f(kv.s[i]), acc);
        }
        s_sh[j] = acc * SCALE;
      }
      __syncthreads();

      if (need_sparse) {
        for (int j = t; j < SEQ; j += 256) {
          unsigned bits = __float_as_uint(fmaf(s_sh[j], swh, sbh));
          u_sh[j] = bits ^ ((bits & 0x80000000u) ? 0xFFFFFFFFu : 0x80000000u);
        }
        __syncthreads();
        unsigned V = 0u;
        for (int bit = 31; bit >= 0; --bit) {
          unsigned cand = V | (1u << bit);
          int c = 0;
          for (int j = t; j < SEQ; j += 256) c += (u_sh[j] >= cand) ? 1 : 0;
          c = block_sum_i(c, redi, t);
          if (c >= KTOP) V = cand;
        }
        int g = 0;
        for (int j = t; j < SEQ; j += 256) g += (u_sh[j] > V) ? 1 : 0;
        g = block_sum_i(g, redi, t);
        int r = KTOP - g;
        for (int j = t; j < SEQ; j += 256) sc_a[j] = (u_sh[j] == V) ? 1 : 0;
        __syncthreads();
        int* src = sc_a; int* dst = sc_b;
        for (int off = 1; off < SEQ; off <<= 1) {
          for (int j = t; j < SEQ; j += 256)
            dst[j] = src[j] + ((j >= off) ? src[j - off] : 0);
          __syncthreads();
          int* tmp = src; src = dst; dst = tmp;
        }
        for (int j = t; j < SEQ; j += 256) {
          bool sp = (u_sh[j] > V) || ((u_sh[j] == V) && (src[j] - 1 < r));
          bool local = (j >= q - HALFW) && (j <= q + HALFW);
          float cv = local ? (sp ? c_ls : c_l) : (sp ? c_s : c_n);
          if (cv < 0.5f) s_sh[j] = -INFINITY;
        }
      } else {
        for (int j = t; j < SEQ; j += 256) {
          bool local = (j >= q - HALFW) && (j <= q + HALFW);
          float cv = local ? c_l : c_n;
          if (cv < 0.5f) s_sh[j] = -INFINITY;
        }
      }
      __syncthreads();

      int anyc = 0;
      for (int j = t; j < SEQ; j += 256) anyc += (s_sh[j] != -INFINITY) ? 1 : 0;
      anyc = block_sum_i(anyc, redi, t);
      if (anyc == 0 && t == 0) s_sh[0] = 0.f;
      __syncthreads();

      float mx = -INFINITY;
      for (int j = t; j < SEQ; j += 256) mx = fmaxf(mx, s_sh[j]);
      mx = block_max_f(mx, redf, t);
      float ls = 0.f;
      for (int j = t; j < SEQ; j += 256) {
        float p = (s_sh[j] == -INFINITY) ? 0.f : expf(s_sh[j] - mx);
        s_sh[j] = p; ls += p;
      }
      ls = block_sum_f(ls, redf, t);
      float inv = 1.f / ls;

      int dd = t & 63, jg2 = t >> 6;
      float acc = 0.f;
      for (int j = jg2; j < SEQ; j += 4)
        acc = fmaf(s_sh[j] * inv, b2f(base[(size_t)j * QKVN + 1024 + ho + dd]), acc);
      float* redo = (float*)u_sh;
      __syncthreads();
      redo[t] = acc;
      __syncthreads();
      if (t < 64) {
        float o = redo[t] + redo[t + 64] + redo[t + 128] + redo[t + 192];
        ao[((size_t)b * SEQ + q) * DIM + ho + t] = __float2bfloat16(o);
      }
      __syncthreads();
    }
  }
}

// ---- launch 5: proj GEMM, 64x64 tile (512 blocks = 2/CU) --------------------
__global__ __launch_bounds__(256) void proj_gemm_kernel(
    const __hip_bfloat16* __restrict__ A, const __hip_bfloat16* __restrict__ B,
    const float* __restrict__ bias, float* __restrict__ C,
    int N, int K) {
  __shared__ __hip_bfloat16 As[64 * 32];
  __shared__ __hip_bfloat16 Bs[64 * 32];
  int t = threadIdx.x;
  int m0 = blockIdx.y * 64;
  int n0 = blockIdx.x * 64;
  int w = t >> 6, l = t & 63;
  int fm = l & 15, fg = l >> 4;
  f32x4 acc[4] = {};
  for (int k0 = 0; k0 < K; k0 += 32) {
    int row = t >> 2, cb = (t & 3) << 4;
    async_load16((const char*)(A + (size_t)(m0 + row) * K + k0) + cb,
                 (char*)As + (size_t)t * 16);
    async_load16((const char*)(B + (size_t)(n0 + row) * K + k0) + cb,
                 (char*)Bs + (size_t)t * 16);
    __syncthreads();
    bf16x8 af = *(const bf16x8*)(As + (size_t)(w * 16 + fm) * 32 + fg * 8);
    bf16x8 bf[4];
#pragma unroll
    for (int j = 0; j < 4; ++j)
      bf[j] = *(const bf16x8*)(Bs + (size_t)(j * 16 + fm) * 32 + fg * 8);
#pragma unroll
    for (int j = 0; j < 4; ++j)
      acc[j] = __builtin_amdgcn_mfma_f32_16x16x32_bf16(af, bf[j], acc[j], 0, 0, 0);
    __syncthreads();
  }
  // C/D layout: col=lane&15, row=(lane>>4)*4+reg
  int mbase = m0 + w * 16 + fg * 4;
#pragma unroll
  for (int j = 0; j < 4; ++j) {
    int n = n0 + j * 16 + fm;
    float bv = bias[n];
#pragma unroll
    for (int r = 0; r < 4; ++r)
      C[(size_t)(mbase + r) * N + n] = acc[j][r] + bv;
  }
}

extern "C" void kernel_launch(void* const* d_in, const int* in_sizes, int n_in,
                              void* d_out, int out_size, void* d_ws, size_t ws_size,
                              hipStream_t stream) {
  const float* x      = (const float*)d_in[0];
  const float* qkv_w  = (const float*)d_in[1];
  const float* proj_w = (const float*)d_in[2];
  const float* proj_b = (const float*)d_in[3];
  const float* ps_w1  = (const float*)d_in[4];
  const float* ps_b1  = (const float*)d_in[5];
  const float* ps_w2  = (const float*)d_in[6];
  const float* ps_b2  = (const float*)d_in[7];
  const float* ps_w3  = (const float*)d_in[8];
  const float* ps_b3  = (const float*)d_in[9];
  const float* pbias  = (const float*)d_in[10];
  const float* sw     = (const float*)d_in[11];
  const float* sb     = (const float*)d_in[12];
  float* out = (float*)d_out;

  char* w = (char*)d_ws;
  float* partial = (float*)w;            w += (size_t)NB * 64 * DIM * 4;
  float* h1 = (float*)w;                 w += (size_t)NB * DIM * 4;
  float* h2 = (float*)w;                 w += (size_t)NB * (DIM / 2) * 4;
  __hip_bfloat16* qkvb = (__hip_bfloat16*)w; w += (size_t)NB * SEQ * QKVN * 2;
  __hip_bfloat16* xb  = (__hip_bfloat16*)w;  w += (size_t)NB * SEQ * DIM * 2;
  __hip_bfloat16* wqb = (__hip_bfloat16*)w;  w += (size_t)QKVN * DIM * 2;
  __hip_bfloat16* wpb = (__hip_bfloat16*)w;  w += (size_t)DIM * DIM * 2;
  __hip_bfloat16* aob = (__hip_bfloat16*)w;  w += (size_t)NB * SEQ * DIM * 2;

  hipLaunchKernelGGL(cvt_pool_kernel, dim3(512), dim3(256), 0, stream,
                     x, qkv_w, proj_w, xb, wqb, wpb, partial);
  hipLaunchKernelGGL(qkv_mlp1_kernel, dim3(768 + 512), dim3(256), 0, stream,
                     xb, wqb, qkvb, QKVN, DIM, partial, ps_w1, ps_b1, h1);
  hipLaunchKernelGGL(mlp2_kernel, dim3(256), dim3(256), 0, stream,
                     h1, ps_w2, ps_b2, h2);
  hipLaunchKernelGGL(attn_kernel, dim3(512 + 1024), dim3(256), 0, stream,
                     h2, ps_w3, ps_b3, pbias, qkvb, sw, sb, aob);
  hipLaunchKernelGGL(proj_gemm_kernel, dim3(DIM / 64, (NB * SEQ) / 64), dim3(256), 0, stream,
                     aob, wpb, proj_b, out, DIM, DIM);
}